// Round 3
// baseline (82.820 us; speedup 1.0000x reference)
//
#include <hip/hip_runtime.h>
#include <hip/hip_bf16.h>
#include <math.h>

#define HALF_LOG_2PI 0.9189385332046727f
#define WIN 32.0f
#define TILE_T 16

typedef float f32x4 __attribute__((ext_vector_type(4)));

// ---------------------------------------------------------------------------
// Kernel A: fused mask-mode detect + cumsum prep + denom.
// One block per batch row (blockDim = Tin). The scanned row lives in LDS, so
// the denom pass (window search + exp-sum per output frame) reads LDS only.
// Mode detect is done redundantly per block (16 KB, L2-served): int32 0/1 ->
// mode 0; f32 0.0/1.0 -> mode 1; else packed bytes -> mode 2. All-zero scan
// region is ambiguous but then all interpretations agree (mask all-false).
// ---------------------------------------------------------------------------
__global__ __launch_bounds__(1024) void prep_denom_k(
        const float* __restrict__ duration, const float* __restrict__ sigma,
        const void* __restrict__ mask,
        float* __restrict__ center, float* __restrict__ amp,
        float* __restrict__ inv_sigma, float* __restrict__ inv_den,
        int* __restrict__ lo_ws, int* __restrict__ cnt_ws,
        int B, int Tin, int Tout) {
    __shared__ float sc[1024], sa[1024], si[1024];
    __shared__ int s_not[2];
    int b = blockIdx.x, tid = threadIdx.x;
    if (tid < 2) s_not[tid] = 0;
    __syncthreads();
    {   // mode detect over first B*Tin/4 words (min buffer size across modes)
        const unsigned int* mw = (const unsigned int*)mask;
        int nwords = (B * Tin) >> 2;
        int nI = 0, nF = 0;
        for (int i = tid; i < nwords; i += blockDim.x) {
            unsigned int w = mw[i];
            nI |= (w != 0u && w != 1u);
            nF |= (w != 0u && w != 0x3F800000u);
        }
        if (nI) atomicOr(&s_not[0], 1);
        if (nF) atomicOr(&s_not[1], 1);
    }
    size_t gi = (size_t)b * Tin + tid;
    float d = duration[gi];
    sc[tid] = d;
    __syncthreads();
    // Hillis-Steele inclusive scan (also acts as fence for s_not)
    for (int off = 1; off < Tin; off <<= 1) {
        float v = (tid >= off) ? sc[tid - off] : 0.0f;
        __syncthreads();
        sc[tid] += v;
        __syncthreads();
    }
    float c = sc[tid] - 0.5f * d;
    int mode = s_not[0] ? (s_not[1] ? 2 : 1) : 0;
    bool m;
    if (mode == 0)      m = ((const int*)mask)[gi] != 0;
    else if (mode == 1) m = ((const float*)mask)[gi] != 0.0f;
    else                m = ((const unsigned char*)mask)[gi] != 0;
    float sg = sigma[gi];
    float a  = m ? 0.0f : __expf(-__logf(sg) - HALF_LOG_2PI);
    float is = 1.0f / sg;
    center[gi] = c; amp[gi] = a; inv_sigma[gi] = is;
    sc[tid] = c; sa[tid] = a; si[tid] = is;   // own-slot writes, then barrier
    __syncthreads();
    // denom for all Tout frames of this row, from LDS
    for (int t = tid; t < Tout; t += blockDim.x) {
        float tf = (float)t;
        int lo = 0, hi = Tin;
        while (lo < hi) {                 // first i with center >= t - WIN
            int mid = (lo + hi) >> 1;
            if (sc[mid] < tf - WIN) lo = mid + 1; else hi = mid;
        }
        float sum = 0.0f;
        int i = lo;
        for (; i < Tin; ++i) {
            float cc = sc[i];
            if (cc > tf + WIN) break;
            float z = (tf - cc) * si[i];
            sum += sa[i] * __expf(-0.5f * z * z);
        }
        size_t g = (size_t)b * Tout + t;
        inv_den[g] = 1.0f / (sum + 1e-8f);
        lo_ws[g]   = lo;
        cnt_ws[g]  = i - lo;
    }
}

// ---------------------------------------------------------------------------
// Kernel B: attn rows + upsample tiles in ONE dispatch (4:1 interleave) so
// write-streaming blocks overlap with L2-read/compute blocks on every CU.
//   attn task: one block per (b,i) row -> coalesced nontemporal float4 writes
//              of the Tout-length row (zeros outside the +/-WIN window).
//   upsample task: one block per (b, TILE_T-frame tile); weights staged in
//              LDS (float4 broadcast reads), memory rows read coalesced and
//              reused across TILE_T accumulators.
// ---------------------------------------------------------------------------
__global__ __launch_bounds__(256) void attn_upsample_k(
        const float* __restrict__ mem, const float* __restrict__ center,
        const float* __restrict__ amp, const float* __restrict__ inv_sigma,
        const float* __restrict__ inv_den, const int* __restrict__ lo_ws,
        const int* __restrict__ cnt_ws, float* __restrict__ attn,
        float* __restrict__ out, int nAttn, int nUp,
        int Tin, int Tout, int D) {
    __shared__ __align__(16) float w_s[TILE_T][128];
    __shared__ float s_iden[TILE_T];
    __shared__ int s_lo, s_cnt;
    int bid = blockIdx.x;
    int tid = threadIdx.x;
    int aid = -1, uid = -1;
    if (nAttn == 4 * nUp) {               // 4:1 interleave for co-residency
        int q = bid / 5, r = bid - q * 5;
        if (r == 4) uid = q; else aid = q * 4 + r;
    } else {
        if (bid < nAttn) aid = bid; else uid = bid - nAttn;
    }

    if (aid >= 0) {
        // ---------------- attn row task ----------------
        int bi = aid;
        int b  = bi / Tin;
        float c = center[bi], a = amp[bi], inv = inv_sigma[bi];
        const float* iden = inv_den + (size_t)b * Tout;
        float* row = attn + (size_t)bi * Tout;
        for (int t4 = tid * 4; t4 < Tout; t4 += 256 * 4) {
            f32x4 rv;
            if ((float)(t4 + 3) < c - WIN || (float)t4 > c + WIN) {
                rv = (f32x4)0.0f;
            } else {
                #pragma unroll
                for (int j = 0; j < 4; ++j) {
                    float dlt = (float)(t4 + j) - c;
                    if (fabsf(dlt) < WIN) {
                        float z = dlt * inv;
                        rv[j] = a * __expf(-0.5f * z * z) * iden[t4 + j];
                    } else rv[j] = 0.0f;
                }
            }
            __builtin_nontemporal_store(rv, (f32x4*)(row + t4));
        }
        return;
    }

    // ---------------- upsample tile task ----------------
    int tpb = Tout / TILE_T;
    int b   = uid / tpb;
    int t0  = (uid - b * tpb) * TILE_T;
    if (tid == 0) {
        size_t g0 = (size_t)b * Tout + t0;
        size_t g1 = g0 + (TILE_T - 1);
        int lo0 = lo_ws[g0];
        int cnt = lo_ws[g1] + cnt_ws[g1] - lo0;
        s_lo  = lo0;
        s_cnt = cnt > 128 ? 128 : cnt;    // mathematically <= 80 (spacing>=1)
    }
    if (tid < TILE_T) s_iden[tid] = inv_den[(size_t)b * Tout + t0 + tid];
    __syncthreads();
    int lo0 = s_lo, wcnt = s_cnt;
    // fill TILE_T x 128 weight slots (8 per thread)
    #pragma unroll
    for (int rep = 0; rep < (TILE_T * 128) / 256; ++rep) {
        int id = tid + rep * 256;
        int f = id >> 7, w = id & 127;
        float wgt = 0.0f;
        int i = lo0 + w;
        if (w < wcnt && i < Tin) {
            size_t gi = (size_t)b * Tin + i;
            float dlt = (float)(t0 + f) - center[gi];
            if (fabsf(dlt) < WIN) {
                float z = dlt * inv_sigma[gi];
                wgt = amp[gi] * __expf(-0.5f * z * z) * s_iden[f];
            }
        }
        w_s[f][w] = wgt;
    }
    __syncthreads();
    for (int d = tid; d < D; d += 256) {
        float acc[TILE_T];
        #pragma unroll
        for (int f = 0; f < TILE_T; ++f) acc[f] = 0.0f;
        const float* mrow = mem + ((size_t)b * Tin + lo0) * D + d;
        int w4 = wcnt & ~3;
        for (int w = 0; w < w4; w += 4) {
            float m0 = mrow[(size_t)(w + 0) * D];
            float m1 = mrow[(size_t)(w + 1) * D];
            float m2 = mrow[(size_t)(w + 2) * D];
            float m3 = mrow[(size_t)(w + 3) * D];
            #pragma unroll
            for (int f = 0; f < TILE_T; ++f) {
                f32x4 wv = *(const f32x4*)&w_s[f][w];   // LDS broadcast b128
                acc[f] += wv.x * m0 + wv.y * m1 + wv.z * m2 + wv.w * m3;
            }
        }
        for (int w = w4; w < wcnt; ++w) {
            float m0 = mrow[(size_t)w * D];
            #pragma unroll
            for (int f = 0; f < TILE_T; ++f) acc[f] += w_s[f][w] * m0;
        }
        float* orow = out + ((size_t)b * Tout + t0) * D + d;
        #pragma unroll
        for (int f = 0; f < TILE_T; ++f)
            __builtin_nontemporal_store(acc[f], orow + (size_t)f * D);
    }
}

extern "C" void kernel_launch(void* const* d_in, const int* in_sizes, int n_in,
                              void* d_out, int out_size, void* d_ws, size_t ws_size,
                              hipStream_t stream) {
    const float* memory   = (const float*)d_in[0];
    const float* duration = (const float*)d_in[1];
    const float* sigma    = (const float*)d_in[2];
    const void*  mask     = d_in[4];          // d_in[3]=output_lengths (unused)

    int B    = in_sizes[3];
    int Tin  = in_sizes[1] / B;
    int D    = in_sizes[0] / (B * Tin);
    int Tout = out_size / (B * (D + Tin));

    float* out_up   = (float*)d_out;
    float* out_attn = out_up + (size_t)B * Tout * D;

    // workspace layout
    float* center = (float*)d_ws;
    float* amp    = center + (size_t)B * Tin;
    float* inv    = amp    + (size_t)B * Tin;
    float* iden   = inv    + (size_t)B * Tin;
    int*   lo     = (int*)(iden + (size_t)B * Tout);
    int*   cnt    = lo + (size_t)B * Tout;

    prep_denom_k<<<B, Tin, 0, stream>>>(duration, sigma, mask,
                                        center, amp, inv, iden, lo, cnt,
                                        B, Tin, Tout);
    int nAttn = B * Tin;
    int nUp   = (B * Tout) / TILE_T;
    attn_upsample_k<<<nAttn + nUp, 256, 0, stream>>>(
        memory, center, amp, inv, iden, lo, cnt,
        out_attn, out_up, nAttn, nUp, Tin, Tout, D);
}

// Round 4
// 62.690 us; speedup vs baseline: 1.3211x; 1.3211x over previous
//
#include <hip/hip_runtime.h>
#include <hip/hip_bf16.h>
#include <math.h>

#define HALF_LOG_2PI 0.9189385332046727f
#define WIN 32.0f
#define TILE_T 16

typedef float f32x4 __attribute__((ext_vector_type(4)));

// ---------------------------------------------------------------------------
// Kernel 1: mask-mode detect (redundant per block, L2-served) + per-row
// cumsum (center) + amp/inv_sigma precompute. One block per batch row,
// blockDim = Tin. Mode: int32 0/1 -> 0; f32 0.0/1.0 -> 1; else bytes -> 2.
// ---------------------------------------------------------------------------
__global__ void prep_k(const float* __restrict__ duration,
                       const float* __restrict__ sigma,
                       const void* __restrict__ mask,
                       float* __restrict__ center,
                       float* __restrict__ amp,
                       float* __restrict__ inv_sigma,
                       int B, int Tin) {
    __shared__ float s[1024];
    __shared__ int s_not[2];
    int b = blockIdx.x, i = threadIdx.x;
    if (i < 2) s_not[i] = 0;
    __syncthreads();
    {   // detect over first B*Tin/4 words (minimum size over all modes)
        const unsigned int* mw = (const unsigned int*)mask;
        int nwords = (B * Tin) >> 2;
        int nI = 0, nF = 0;
        for (int k = i; k < nwords; k += blockDim.x) {
            unsigned int w = mw[k];
            nI |= (w != 0u && w != 1u);
            nF |= (w != 0u && w != 0x3F800000u);
        }
        if (nI) atomicOr(&s_not[0], 1);
        if (nF) atomicOr(&s_not[1], 1);
    }
    size_t gi = (size_t)b * Tin + i;
    float d = duration[gi];
    s[i] = d;
    __syncthreads();
    // Hillis-Steele inclusive scan
    for (int off = 1; off < Tin; off <<= 1) {
        float v = (i >= off) ? s[i - off] : 0.0f;
        __syncthreads();
        s[i] += v;
        __syncthreads();
    }
    float c = s[i] - 0.5f * d;
    int mode = s_not[0] ? (s_not[1] ? 2 : 1) : 0;
    bool m;
    if (mode == 0)      m = ((const int*)mask)[gi] != 0;
    else if (mode == 1) m = ((const float*)mask)[gi] != 0.0f;
    else                m = ((const unsigned char*)mask)[gi] != 0;
    float sg = sigma[gi];
    center[gi]    = c;
    inv_sigma[gi] = 1.0f / sg;
    amp[gi]       = m ? 0.0f : __expf(-__logf(sg) - HALF_LOG_2PI);
}

// ---------------------------------------------------------------------------
// Kernel 2: inv_den[b,t] = 1/(sum_i alignment + 1e-8); window lo/cnt per
// (b,t). Grid (Tout/256, B), 256 threads, row staged in LDS.
// ---------------------------------------------------------------------------
__global__ __launch_bounds__(256) void denom_k(
        const float* __restrict__ center, const float* __restrict__ amp,
        const float* __restrict__ inv_sigma,
        float* __restrict__ inv_den, int* __restrict__ lo_out,
        int* __restrict__ cnt_out, int Tin, int Tout) {
    __shared__ float sc[1024], sa[1024], si[1024];
    int b = blockIdx.y;
    int t = blockIdx.x * 256 + threadIdx.x;
    for (int i = threadIdx.x; i < Tin; i += 256) {
        size_t g = (size_t)b * Tin + i;
        sc[i] = center[g]; sa[i] = amp[g]; si[i] = inv_sigma[g];
    }
    __syncthreads();
    if (t >= Tout) return;
    float tf = (float)t;
    int lo = 0, hi = Tin;
    while (lo < hi) {                 // first i with center >= t - WIN
        int mid = (lo + hi) >> 1;
        if (sc[mid] < tf - WIN) lo = mid + 1; else hi = mid;
    }
    float sum = 0.0f;
    int i = lo;
    for (; i < Tin; ++i) {
        float cc = sc[i];
        if (cc > tf + WIN) break;
        float z = (tf - cc) * si[i];
        sum += sa[i] * __expf(-0.5f * z * z);
    }
    size_t g = (size_t)b * Tout + t;
    inv_den[g]  = 1.0f / (sum + 1e-8f);
    lo_out[g]   = lo;
    cnt_out[g]  = i - lo;
}

// ---------------------------------------------------------------------------
// Kernel 3: attn rows. One block per (b,i); coalesced nontemporal f32x4
// writes of the Tout-length row (zeros outside the +/-WIN window).
// ---------------------------------------------------------------------------
__global__ __launch_bounds__(256) void attn_k(
        const float* __restrict__ center, const float* __restrict__ amp,
        const float* __restrict__ inv_sigma, const float* __restrict__ inv_den,
        float* __restrict__ attn, int Tin, int Tout) {
    int bi = blockIdx.x;
    int b  = bi / Tin;
    float c = center[bi], a = amp[bi], inv = inv_sigma[bi];
    const float* iden = inv_den + (size_t)b * Tout;
    float* row = attn + (size_t)bi * Tout;
    for (int t4 = threadIdx.x * 4; t4 < Tout; t4 += 256 * 4) {
        f32x4 rv;
        if ((float)(t4 + 3) < c - WIN || (float)t4 > c + WIN) {
            rv = (f32x4)0.0f;
        } else {
            #pragma unroll
            for (int j = 0; j < 4; ++j) {
                float dlt = (float)(t4 + j) - c;
                if (fabsf(dlt) < WIN) {
                    float z = dlt * inv;
                    rv[j] = a * __expf(-0.5f * z * z) * iden[t4 + j];
                } else rv[j] = 0.0f;
            }
        }
        __builtin_nontemporal_store(rv, (f32x4*)(row + t4));
    }
}

// ---------------------------------------------------------------------------
// Kernel 4: upsampled[b,t,d] = sum_w attn[b,lo+w,t] * memory[b,lo+w,d].
// Block = (b, TILE_T-frame tile); 256 threads over D. Weights staged in LDS
// (f32x4 broadcast reads); memory rows read coalesced, reused TILE_T ways.
// ---------------------------------------------------------------------------
__global__ __launch_bounds__(256) void upsample_k(
        const float* __restrict__ mem, const float* __restrict__ center,
        const float* __restrict__ amp, const float* __restrict__ inv_sigma,
        const float* __restrict__ inv_den, const int* __restrict__ lo_ws,
        const int* __restrict__ cnt_ws, float* __restrict__ out,
        int Tin, int Tout, int D) {
    __shared__ __align__(16) float w_s[TILE_T][128];
    __shared__ float s_iden[TILE_T];
    __shared__ int s_lo, s_cnt;
    int nwg = gridDim.x;
    int wid = blockIdx.x;
    int work = wid;
    if ((nwg & 7) == 0) {                    // XCD-chunked swizzle (8 XCDs)
        int chunk = nwg >> 3;
        work = (wid & 7) * chunk + (wid >> 3);
    }
    int tpb = Tout / TILE_T;
    int b   = work / tpb;
    int t0  = (work - b * tpb) * TILE_T;
    int tid = threadIdx.x;
    if (tid == 0) {
        size_t g0 = (size_t)b * Tout + t0;
        size_t g1 = g0 + (TILE_T - 1);
        int lo0 = lo_ws[g0];
        int cnt = lo_ws[g1] + cnt_ws[g1] - lo0;
        s_lo  = lo0;
        s_cnt = cnt > 128 ? 128 : cnt;    // mathematically <= ~81 (spacing>=1)
    }
    if (tid < TILE_T) s_iden[tid] = inv_den[(size_t)b * Tout + t0 + tid];
    __syncthreads();
    int lo0 = s_lo, wcnt = s_cnt;
    // fill TILE_T x 128 weight slots (TILE_T*128/256 per thread)
    #pragma unroll
    for (int rep = 0; rep < (TILE_T * 128) / 256; ++rep) {
        int id = tid + rep * 256;
        int f = id >> 7, w = id & 127;
        float wgt = 0.0f;
        int i = lo0 + w;
        if (w < wcnt && i < Tin) {
            size_t gi = (size_t)b * Tin + i;
            float dlt = (float)(t0 + f) - center[gi];
            if (fabsf(dlt) < WIN) {
                float z = dlt * inv_sigma[gi];
                wgt = amp[gi] * __expf(-0.5f * z * z) * s_iden[f];
            }
        }
        w_s[f][w] = wgt;
    }
    __syncthreads();
    for (int d = tid; d < D; d += 256) {
        float acc[TILE_T];
        #pragma unroll
        for (int f = 0; f < TILE_T; ++f) acc[f] = 0.0f;
        const float* mrow = mem + ((size_t)b * Tin + lo0) * D + d;
        int w4 = wcnt & ~3;
        for (int w = 0; w < w4; w += 4) {
            float m0 = mrow[(size_t)(w + 0) * D];
            float m1 = mrow[(size_t)(w + 1) * D];
            float m2 = mrow[(size_t)(w + 2) * D];
            float m3 = mrow[(size_t)(w + 3) * D];
            #pragma unroll
            for (int f = 0; f < TILE_T; ++f) {
                f32x4 wv = *(const f32x4*)&w_s[f][w];   // LDS broadcast b128
                acc[f] += wv.x * m0 + wv.y * m1 + wv.z * m2 + wv.w * m3;
            }
        }
        for (int w = w4; w < wcnt; ++w) {
            float m0 = mrow[(size_t)w * D];
            #pragma unroll
            for (int f = 0; f < TILE_T; ++f) acc[f] += w_s[f][w] * m0;
        }
        float* orow = out + ((size_t)b * Tout + t0) * D + d;
        #pragma unroll
        for (int f = 0; f < TILE_T; ++f)
            __builtin_nontemporal_store(acc[f], orow + (size_t)f * D);
    }
}

extern "C" void kernel_launch(void* const* d_in, const int* in_sizes, int n_in,
                              void* d_out, int out_size, void* d_ws, size_t ws_size,
                              hipStream_t stream) {
    const float* memory   = (const float*)d_in[0];
    const float* duration = (const float*)d_in[1];
    const float* sigma    = (const float*)d_in[2];
    const void*  mask     = d_in[4];          // d_in[3]=output_lengths (unused)

    int B    = in_sizes[3];
    int Tin  = in_sizes[1] / B;
    int D    = in_sizes[0] / (B * Tin);
    int Tout = out_size / (B * (D + Tin));

    float* out_up   = (float*)d_out;
    float* out_attn = out_up + (size_t)B * Tout * D;

    // workspace layout
    float* center = (float*)d_ws;
    float* amp    = center + (size_t)B * Tin;
    float* inv    = amp    + (size_t)B * Tin;
    float* iden   = inv    + (size_t)B * Tin;
    int*   lo     = (int*)(iden + (size_t)B * Tout);
    int*   cnt    = lo + (size_t)B * Tout;

    prep_k<<<B, Tin, 0, stream>>>(duration, sigma, mask,
                                  center, amp, inv, B, Tin);
    denom_k<<<dim3((Tout + 255) / 256, B), 256, 0, stream>>>(
        center, amp, inv, iden, lo, cnt, Tin, Tout);
    attn_k<<<B * Tin, 256, 0, stream>>>(center, amp, inv, iden,
                                        out_attn, Tin, Tout);
    upsample_k<<<(B * Tout) / TILE_T, 256, 0, stream>>>(
        memory, center, amp, inv, iden, lo, cnt, out_up, Tin, Tout, D);
}